// Round 5
// baseline (239.910 us; speedup 1.0000x reference)
//
#include <hip/hip_runtime.h>

// 8x8 block DCT: C = A * B * A^T per non-overlapping block.
// R2:  LDS-staged coalesced nt stores, XOR-swizzle (measured 0 bank conflicts);
//      nt stores keep input L3-resident (measured FETCH = 65.6 MB = half input).
// R7:  R4 post-mortem: per-load asm pins let the compiler interleave
//      load->pin->consume (VGPR stayed 48, ~4KB/wave MLP, 80.5us, latency-
//      convoy-bound: VALU 17%, HBM 31%, occ 34%). fillBuffer control: 6.5TB/s
//      at 9% occupancy -> per-wave pipelining beats TLP. New structure:
//      - 128-thread wg = one image block-row (32KB in / 32KB out), grid=1024,
//        ALL-RESIDENT (4 wg/CU exactly), each wg processes ITERS=4 rows.
//      - software pipeline: next row's 16 loads issue after stage1 frees r;
//        __syncthreads fences keep them before the store phase; first use is
//        next iteration -> ~2000cy of LDS+store work hides ~900cy HBM latency.
//      - NO asm pins (they forced waits at issue).
//      - even/odd DCT butterfly: 1024 -> ~640 VALU ops per block.

typedef float f32x4 __attribute__((ext_vector_type(4)));

#define ITERS 4

__global__ __launch_bounds__(128, 2) void dct8x8_kernel(const float* __restrict__ x,
                                                        float* __restrict__ out) {
    constexpr float A[8][8] = {
        { 0.35355339059327373f,  0.35355339059327373f,  0.35355339059327373f,  0.35355339059327373f,
          0.35355339059327373f,  0.35355339059327373f,  0.35355339059327373f,  0.35355339059327373f},
        { 0.49039264020161522f,  0.41573480615127262f,  0.27778511650980114f,  0.09754516100806417f,
         -0.09754516100806417f, -0.27778511650980114f, -0.41573480615127262f, -0.49039264020161522f},
        { 0.46193976625564337f,  0.19134171618254492f, -0.19134171618254492f, -0.46193976625564337f,
         -0.46193976625564337f, -0.19134171618254492f,  0.19134171618254492f,  0.46193976625564337f},
        { 0.41573480615127262f, -0.09754516100806417f, -0.49039264020161522f, -0.27778511650980114f,
          0.27778511650980114f,  0.49039264020161522f,  0.09754516100806417f, -0.41573480615127262f},
        { 0.35355339059327373f, -0.35355339059327373f, -0.35355339059327373f,  0.35355339059327373f,
          0.35355339059327373f, -0.35355339059327373f, -0.35355339059327373f,  0.35355339059327373f},
        { 0.27778511650980114f, -0.49039264020161522f,  0.09754516100806417f,  0.41573480615127262f,
         -0.41573480615127262f, -0.09754516100806417f,  0.49039264020161522f, -0.27778511650980114f},
        { 0.19134171618254492f, -0.46193976625564337f,  0.46193976625564337f, -0.19134171618254492f,
         -0.19134171618254492f,  0.46193976625564337f, -0.46193976625564337f,  0.19134171618254492f},
        { 0.09754516100806417f, -0.27778511650980114f,  0.41573480615127262f, -0.49039264020161522f,
          0.49039264020161522f, -0.41573480615127262f,  0.27778511650980114f, -0.09754516100806417f},
    };

    __shared__ f32x4 lds4[2048];  // 32 KiB: full output staging for one block-row

    const int tl = threadIdx.x;            // 0..127 == block-column bj
    const int g0 = blockIdx.x * ITERS;     // first block-row group (global)
    const int n  = g0 >> 7;                // image index
    const int bi = g0 & 127;               // block-row within image (multiple of 4)

    // rows bi*8 .. bi*8+7 of image n, this thread's 8-float column window
    const float* src = x + (((size_t)n << 20) + ((size_t)bi << 13) + (tl << 3));

    // Prologue: load the first block-row's 8 rows (16 x dwordx4).
    f32x4 r[16];
#pragma unroll
    for (int j = 0; j < 8; ++j) {
        r[2 * j]     = *reinterpret_cast<const f32x4*>(src + j * 1024);
        r[2 * j + 1] = *reinterpret_cast<const f32x4*>(src + j * 1024 + 4);
    }

    for (int it = 0; it < ITERS; ++it) {
        // Stage 1 (butterfly): Mt[j][m] = sum_l B[j][l] * A[m][l].
        // Even m rows of A are symmetric, odd antisymmetric ->
        // fold b into u/v (8 adds), then 4-FMA dots.
        float Mt[64];
#pragma unroll
        for (int j = 0; j < 8; ++j) {
            const float b0 = r[2*j].x, b1 = r[2*j].y, b2 = r[2*j].z, b3 = r[2*j].w;
            const float b4 = r[2*j+1].x, b5 = r[2*j+1].y, b6 = r[2*j+1].z, b7 = r[2*j+1].w;
            const float u0 = b0 + b7, u1 = b1 + b6, u2 = b2 + b5, u3 = b3 + b4;
            const float v0 = b0 - b7, v1 = b1 - b6, v2 = b2 - b5, v3 = b3 - b4;
#pragma unroll
            for (int m = 0; m < 8; m += 2) {
                float e = u0 * A[m][0];
                e = fmaf(u1, A[m][1], e);
                e = fmaf(u2, A[m][2], e);
                e = fmaf(u3, A[m][3], e);
                Mt[j * 8 + m] = e;
                float o = v0 * A[m + 1][0];
                o = fmaf(v1, A[m + 1][1], o);
                o = fmaf(v2, A[m + 1][2], o);
                o = fmaf(v3, A[m + 1][3], o);
                Mt[j * 8 + m + 1] = o;
            }
        }

        // Pipeline: r is dead now -> issue next block-row's loads. Their first
        // use is next iteration's stage 1; the __syncthreads fences below keep
        // the issue point here, so stage2+LDS+store latency covers HBM latency.
        if (it + 1 < ITERS) {
            const float* nsrc = src + (it + 1) * 8192;
#pragma unroll
            for (int j = 0; j < 8; ++j) {
                r[2 * j]     = *reinterpret_cast<const f32x4*>(nsrc + j * 1024);
                r[2 * j + 1] = *reinterpret_cast<const f32x4*>(nsrc + j * 1024 + 4);
            }
        }

        // Stage 2 (butterfly over j): c[i][m] = sum_j A[i][j] * Mt[j][m].
        float c[64];
#pragma unroll
        for (int m = 0; m < 8; ++m) {
            const float u0 = Mt[0*8+m] + Mt[7*8+m];
            const float u1 = Mt[1*8+m] + Mt[6*8+m];
            const float u2 = Mt[2*8+m] + Mt[5*8+m];
            const float u3 = Mt[3*8+m] + Mt[4*8+m];
            const float v0 = Mt[0*8+m] - Mt[7*8+m];
            const float v1 = Mt[1*8+m] - Mt[6*8+m];
            const float v2 = Mt[2*8+m] - Mt[5*8+m];
            const float v3 = Mt[3*8+m] - Mt[4*8+m];
#pragma unroll
            for (int i = 0; i < 8; i += 2) {
                float e = u0 * A[i][0];
                e = fmaf(u1, A[i][1], e);
                e = fmaf(u2, A[i][2], e);
                e = fmaf(u3, A[i][3], e);
                c[i * 8 + m] = e;
                float o = v0 * A[i + 1][0];
                o = fmaf(v1, A[i + 1][1], o);
                o = fmaf(v2, A[i + 1][2], o);
                o = fmaf(v3, A[i + 1][3], o);
                c[(i + 1) * 8 + m] = o;
            }
        }

        // Stage C into LDS (XOR swizzle; write <=2-way conflicts, free).
#pragma unroll
        for (int i = 0; i < 8; ++i) {
            const int f0 = tl * 16 + i * 2;   // logical float4 index
            f32x4 w0; w0.x = c[i*8+0]; w0.y = c[i*8+1]; w0.z = c[i*8+2]; w0.w = c[i*8+3];
            f32x4 w1; w1.x = c[i*8+4]; w1.y = c[i*8+5]; w1.z = c[i*8+6]; w1.w = c[i*8+7];
            lds4[f0 ^ (tl & 15)]       = w0;
            lds4[(f0 + 1) ^ (tl & 15)] = w1;
        }
        __syncthreads();

        // Cooperative coalesced nontemporal store: 2048 float4 = 32 KiB
        // contiguous; 128 threads x 16 B = 2 KiB per instruction.
        f32x4* dst4 = reinterpret_cast<f32x4*>(out + ((size_t)(g0 + it) << 13));
#pragma unroll
        for (int s = 0; s < 16; ++s) {
            const int f4 = s * 128 + tl;
            __builtin_nontemporal_store(lds4[f4 ^ ((f4 >> 4) & 15)], dst4 + f4);
        }
        __syncthreads();  // protect LDS reuse by the next iteration
    }
}

extern "C" void kernel_launch(void* const* d_in, const int* in_sizes, int n_in,
                              void* d_out, int out_size, void* d_ws, size_t ws_size,
                              hipStream_t stream) {
    const float* x = (const float*)d_in[0];
    float* out = (float*)d_out;

    const int nblocks = out_size / 64;            // 524288 8x8 blocks
    const int ngroups = nblocks / 128;            // 4096 block-rows
    const int grid = ngroups / ITERS;             // 1024 workgroups, all-resident
    dct8x8_kernel<<<grid, 128, 0, stream>>>(x, out);
}

// Round 6
// 239.754 us; speedup vs baseline: 1.0007x; 1.0007x over previous
//
#include <hip/hip_runtime.h>

// 8x8 block DCT: C = A * B * A^T per non-overlapping block.
// R2:  LDS-staged coalesced nt stores, XOR-swizzle (0 bank conflicts);
//      nt stores keep input L3-resident (FETCH = 65.6 MB = half input).
// R7:  persistent 128-thread wgs (1 thread = 1 block, ITERS=4 block-rows),
//      software-pipelined loads, even/odd butterfly (VALU 17%->6%, VGPR 92).
// R8:  R7 was flat (84us) because BOTH __syncthreads emit s_waitcnt vmcnt(0)
//      (HIP semantics): barrier #1 drained the just-issued prefetch loads
//      (killing the pipeline) and barrier #2 drained the 16 nt stores (full
//      store-ack round trip exposed every iteration). Neither barrier needs
//      vmcnt: #1 orders LDS writes->reads (lgkmcnt only), #2 protects LDS
//      reuse (ds_read part of the stores, lgkmcnt only). Replace both with
//      raw s_barrier + lgkmcnt(0): prefetch loads now drain only at their
//      consumer (counted vmcnt before next stage 1), stores never.

typedef float f32x4 __attribute__((ext_vector_type(4)));

#define ITERS 4

// Barrier that does NOT drain vmcnt: LDS-visibility only.
__device__ __forceinline__ void lds_barrier() {
    asm volatile("s_waitcnt lgkmcnt(0)" ::: "memory");
    __builtin_amdgcn_s_barrier();
}

__global__ __launch_bounds__(128, 2) void dct8x8_kernel(const float* __restrict__ x,
                                                        float* __restrict__ out) {
    constexpr float A[8][8] = {
        { 0.35355339059327373f,  0.35355339059327373f,  0.35355339059327373f,  0.35355339059327373f,
          0.35355339059327373f,  0.35355339059327373f,  0.35355339059327373f,  0.35355339059327373f},
        { 0.49039264020161522f,  0.41573480615127262f,  0.27778511650980114f,  0.09754516100806417f,
         -0.09754516100806417f, -0.27778511650980114f, -0.41573480615127262f, -0.49039264020161522f},
        { 0.46193976625564337f,  0.19134171618254492f, -0.19134171618254492f, -0.46193976625564337f,
         -0.46193976625564337f, -0.19134171618254492f,  0.19134171618254492f,  0.46193976625564337f},
        { 0.41573480615127262f, -0.09754516100806417f, -0.49039264020161522f, -0.27778511650980114f,
          0.27778511650980114f,  0.49039264020161522f,  0.09754516100806417f, -0.41573480615127262f},
        { 0.35355339059327373f, -0.35355339059327373f, -0.35355339059327373f,  0.35355339059327373f,
          0.35355339059327373f, -0.35355339059327373f, -0.35355339059327373f,  0.35355339059327373f},
        { 0.27778511650980114f, -0.49039264020161522f,  0.09754516100806417f,  0.41573480615127262f,
         -0.41573480615127262f, -0.09754516100806417f,  0.49039264020161522f, -0.27778511650980114f},
        { 0.19134171618254492f, -0.46193976625564337f,  0.46193976625564337f, -0.19134171618254492f,
         -0.19134171618254492f,  0.46193976625564337f, -0.46193976625564337f,  0.19134171618254492f},
        { 0.09754516100806417f, -0.27778511650980114f,  0.41573480615127262f, -0.49039264020161522f,
          0.49039264020161522f, -0.41573480615127262f,  0.27778511650980114f, -0.09754516100806417f},
    };

    __shared__ f32x4 lds4[2048];  // 32 KiB: full output staging for one block-row

    const int tl = threadIdx.x;            // 0..127 == block-column bj
    const int g0 = blockIdx.x * ITERS;     // first block-row group (global)
    const int n  = g0 >> 7;                // image index
    const int bi = g0 & 127;               // block-row within image (multiple of 4)

    // rows bi*8 .. bi*8+7 of image n, this thread's 8-float column window
    const float* src = x + (((size_t)n << 20) + ((size_t)bi << 13) + (tl << 3));

    // Prologue: load the first block-row's 8 rows (16 x dwordx4).
    f32x4 r[16];
#pragma unroll
    for (int j = 0; j < 8; ++j) {
        r[2 * j]     = *reinterpret_cast<const f32x4*>(src + j * 1024);
        r[2 * j + 1] = *reinterpret_cast<const f32x4*>(src + j * 1024 + 4);
    }

    for (int it = 0; it < ITERS; ++it) {
        // Stage 1 (butterfly): Mt[j][m] = sum_l B[j][l] * A[m][l].
        float Mt[64];
#pragma unroll
        for (int j = 0; j < 8; ++j) {
            const float b0 = r[2*j].x, b1 = r[2*j].y, b2 = r[2*j].z, b3 = r[2*j].w;
            const float b4 = r[2*j+1].x, b5 = r[2*j+1].y, b6 = r[2*j+1].z, b7 = r[2*j+1].w;
            const float u0 = b0 + b7, u1 = b1 + b6, u2 = b2 + b5, u3 = b3 + b4;
            const float v0 = b0 - b7, v1 = b1 - b6, v2 = b2 - b5, v3 = b3 - b4;
#pragma unroll
            for (int m = 0; m < 8; m += 2) {
                float e = u0 * A[m][0];
                e = fmaf(u1, A[m][1], e);
                e = fmaf(u2, A[m][2], e);
                e = fmaf(u3, A[m][3], e);
                Mt[j * 8 + m] = e;
                float o = v0 * A[m + 1][0];
                o = fmaf(v1, A[m + 1][1], o);
                o = fmaf(v2, A[m + 1][2], o);
                o = fmaf(v3, A[m + 1][3], o);
                Mt[j * 8 + m + 1] = o;
            }
        }

        // Pipeline: r is dead now -> issue next block-row's loads. With
        // lgkm-only barriers below, these stay IN FLIGHT until next
        // iteration's stage 1 (counted vmcnt at the consumer).
        if (it + 1 < ITERS) {
            const float* nsrc = src + (it + 1) * 8192;
#pragma unroll
            for (int j = 0; j < 8; ++j) {
                r[2 * j]     = *reinterpret_cast<const f32x4*>(nsrc + j * 1024);
                r[2 * j + 1] = *reinterpret_cast<const f32x4*>(nsrc + j * 1024 + 4);
            }
        }

        // Stage 2 (butterfly over j): c[i][m] = sum_j A[i][j] * Mt[j][m].
        float c[64];
#pragma unroll
        for (int m = 0; m < 8; ++m) {
            const float u0 = Mt[0*8+m] + Mt[7*8+m];
            const float u1 = Mt[1*8+m] + Mt[6*8+m];
            const float u2 = Mt[2*8+m] + Mt[5*8+m];
            const float u3 = Mt[3*8+m] + Mt[4*8+m];
            const float v0 = Mt[0*8+m] - Mt[7*8+m];
            const float v1 = Mt[1*8+m] - Mt[6*8+m];
            const float v2 = Mt[2*8+m] - Mt[5*8+m];
            const float v3 = Mt[3*8+m] - Mt[4*8+m];
#pragma unroll
            for (int i = 0; i < 8; i += 2) {
                float e = u0 * A[i][0];
                e = fmaf(u1, A[i][1], e);
                e = fmaf(u2, A[i][2], e);
                e = fmaf(u3, A[i][3], e);
                c[i * 8 + m] = e;
                float o = v0 * A[i + 1][0];
                o = fmaf(v1, A[i + 1][1], o);
                o = fmaf(v2, A[i + 1][2], o);
                o = fmaf(v3, A[i + 1][3], o);
                c[(i + 1) * 8 + m] = o;
            }
        }

        // Stage C into LDS (XOR swizzle; <=2-way conflicts, free).
#pragma unroll
        for (int i = 0; i < 8; ++i) {
            const int f0 = tl * 16 + i * 2;   // logical float4 index
            f32x4 w0; w0.x = c[i*8+0]; w0.y = c[i*8+1]; w0.z = c[i*8+2]; w0.w = c[i*8+3];
            f32x4 w1; w1.x = c[i*8+4]; w1.y = c[i*8+5]; w1.z = c[i*8+6]; w1.w = c[i*8+7];
            lds4[f0 ^ (tl & 15)]       = w0;
            lds4[(f0 + 1) ^ (tl & 15)] = w1;
        }
        lds_barrier();  // LDS writes visible; prefetch loads stay in flight

        // Cooperative coalesced nontemporal store: 2048 float4 = 32 KiB
        // contiguous; 128 threads x 16 B = 2 KiB per instruction.
        f32x4* dst4 = reinterpret_cast<f32x4*>(out + ((size_t)(g0 + it) << 13));
#pragma unroll
        for (int s = 0; s < 16; ++s) {
            const int f4 = s * 128 + tl;
            __builtin_nontemporal_store(lds4[f4 ^ ((f4 >> 4) & 15)], dst4 + f4);
        }
        // LDS reuse only needs the ds_read half of the stores retired
        // (lgkmcnt); the global stores themselves are never drained.
        lds_barrier();
    }
}

extern "C" void kernel_launch(void* const* d_in, const int* in_sizes, int n_in,
                              void* d_out, int out_size, void* d_ws, size_t ws_size,
                              hipStream_t stream) {
    const float* x = (const float*)d_in[0];
    float* out = (float*)d_out;

    const int nblocks = out_size / 64;            // 524288 8x8 blocks
    const int ngroups = nblocks / 128;            // 4096 block-rows
    const int grid = ngroups / ITERS;             // 1024 workgroups, all-resident
    dct8x8_kernel<<<grid, 128, 0, stream>>>(x, out);
}